// Round 6
// baseline (560.230 us; speedup 1.0000x reference)
//
#include <hip/hip_runtime.h>

#define BB 16
#define NN 8192
#define DMODEL 256
#define DKK 64
#define DVV 64
#define NQQ 256
#define TOK 32
#define MARGIN 0.02f
#define CAP 32768
#define GRID 256
#define TPB ((BB * NN / TOK) / GRID)   // 16 tiles per block

typedef __attribute__((ext_vector_type(8))) short bf16x8;
typedef __attribute__((ext_vector_type(4))) float f32x4;

// RNE split of f32 into bf16 hi + bf16 lo (x ~= hi + lo, |err| ~ 2^-17 |x|)
__device__ __forceinline__ void split_bf16(float v, unsigned short& h, unsigned short& lo) {
  unsigned u = __float_as_uint(v);
  unsigned hr = (u + 0x7FFFu + ((u >> 16) & 1u)) & 0xFFFF0000u;
  h = (unsigned short)(hr >> 16);
  float r = v - __uint_as_float(hr);
  unsigned ul = __float_as_uint(r);
  lo = (unsigned short)((ul + 0x7FFFu + ((ul >> 16) & 1u)) >> 16);
}

// prep: qk = q @ w_ks (f32, for recheck), split-fragments qhf/qlf, MT = (w_fc @ w_vs)^T
__global__ __launch_bounds__(256) void prep_kernel(
    const float* __restrict__ q, const float* __restrict__ w_ks,
    const float* __restrict__ w_vs, const float* __restrict__ w_fc,
    float* __restrict__ qk, float* __restrict__ MT,
    unsigned short* __restrict__ qhf, unsigned short* __restrict__ qlf) {
  __shared__ float sbuf[DKK];
  const int tid = threadIdx.x;
  const int blk = blockIdx.x;
  if (blk < NQQ) {
    const int s = blk;
    if (tid < DKK) sbuf[tid] = q[s * DKK + tid];
    __syncthreads();
    float acc = 0.f;
#pragma unroll
    for (int k = 0; k < DKK; ++k) acc = fmaf(sbuf[k], w_ks[k * DMODEL + tid], acc);
    qk[s * DMODEL + tid] = acc;
    // B fragment layout: elem idx = ((kstep*16 + stile)*64 + (kg*16 + s15))*8 + jj
    int d = tid;
    int kstep = d >> 5, kg = (d >> 3) & 3, jj = d & 7;
    int stile = s >> 4, s15 = s & 15;
    int e = (((kstep * 16 + stile) * 64) + (kg * 16 + s15)) * 8 + jj;
    unsigned short hb, lb;
    split_bf16(acc, hb, lb);
    qhf[e] = hb; qlf[e] = lb;
  } else {
    const int dm = blk - NQQ;
    if (tid < DVV) sbuf[tid] = w_vs[tid * DMODEL + dm];
    __syncthreads();
    float acc = 0.f;
#pragma unroll
    for (int v = 0; v < DVV; ++v) acc = fmaf(w_fc[tid * DVV + v], sbuf[v], acc);
    MT[dm * DMODEL + tid] = acc;
  }
}

// main: persistent blocks, B-frags in registers, dbuf LDS staging,
// split-bf16 MFMA scores, top-2 argmax + margin list, one-hot, reg-scatter S
__global__ __launch_bounds__(512, 2) void score_kernel(
    const float* __restrict__ x, const unsigned short* __restrict__ qhf,
    const unsigned short* __restrict__ qlf,
    float* __restrict__ S, float* __restrict__ hard,
    unsigned* __restrict__ cnt, unsigned* __restrict__ list) {
  __shared__ unsigned short xs_h[2][8192];  // [buf][kstep(8)][tile(2)][lane(64)][8]
  __shared__ unsigned short xs_l[2][8192];  // 2 x 16 KB each -> 64 KB total
  __shared__ float rm1[8][TOK];
  __shared__ float rm2[8][TOK];
  __shared__ int   ri1[8][TOK];
  __shared__ int   idx_s[TOK];

  const int tid = threadIdx.x;
  const int w = tid >> 6;       // wave 0..7 -> slot range w*32..w*32+31
  const int l = tid & 63;       // lane

  // ---- B fragments: load once, keep in VGPRs (32 frags = 128 VGPR) ----
  const bf16x8* bhp = (const bf16x8*)qhf;
  const bf16x8* blp = (const bf16x8*)qlf;
  bf16x8 Bh[8][2], Bl[8][2];
#pragma unroll
  for (int k = 0; k < 8; ++k)
#pragma unroll
    for (int jj = 0; jj < 2; ++jj) {
      Bh[k][jj] = bhp[(k * 16 + w * 2 + jj) * 64 + l];
      Bl[k][jj] = blp[(k * 16 + w * 2 + jj) * 64 + l];
    }

  // staging geometry: it-th element u = it*512+tid -> (tok, c4)
  // e = ((kstep*2 + ti)*64 + (kg*16 + t15))*8 + j0
  int eidx[4]; int gidx[4];
#pragma unroll
  for (int it = 0; it < 4; ++it) {
    int u = it * 512 + tid;
    int tok = u >> 6, c4 = u & 63;
    int kstep = c4 >> 3, kg = (c4 >> 1) & 3, j0 = (c4 & 1) * 4;
    int ti = tok >> 4, t15 = tok & 15;
    eidx[it] = (((kstep * 2 + ti) * 64) + (kg * 16 + t15)) * 8 + j0;
    gidx[it] = tok * 64 + c4;
  }
  // scatter-from-regs geometry: it-th element -> tok = it*8 + w, d0 = (tid&63)*4
  const int sc_tok_base = tid >> 6;   // == w
  const int sc_d0 = (tid & 63) * 4;

  const int tile0 = blockIdx.x * TPB;

  // prefetch tile 0
  float4 xr[4];
  {
    int b = tile0 >> 8, n0 = (tile0 & 255) * TOK;
    const float4* xb4 = (const float4*)(x + ((size_t)b * NN + n0) * DMODEL);
#pragma unroll
    for (int it = 0; it < 4; ++it) xr[it] = xb4[gidx[it]];
  }

  const int s15 = l & 15, g4 = l >> 4;

  for (int tt = 0; tt < TPB; ++tt) {
    const int tile = tile0 + tt;
    const int b = tile >> 8;
    const int n0 = (tile & 255) * TOK;
    const int buf = tt & 1;

    // ---- split + write current tile regs to LDS; keep a copy for scatter ----
    float4 xr2[4];
#pragma unroll
    for (int it = 0; it < 4; ++it) {
      xr2[it] = xr[it];
      ushort4 hh, ll;
      split_bf16(xr[it].x, hh.x, ll.x);
      split_bf16(xr[it].y, hh.y, ll.y);
      split_bf16(xr[it].z, hh.z, ll.z);
      split_bf16(xr[it].w, hh.w, ll.w);
      *(ushort4*)(&xs_h[buf][eidx[it]]) = hh;
      *(ushort4*)(&xs_l[buf][eidx[it]]) = ll;
    }
    // ---- prefetch next tile into regs (HBM latency hides under compute) ----
    if (tt + 1 < TPB) {
      int tile2 = tile + 1;
      int b2 = tile2 >> 8, n02 = (tile2 & 255) * TOK;
      const float4* xb4 = (const float4*)(x + ((size_t)b2 * NN + n02) * DMODEL);
#pragma unroll
      for (int it = 0; it < 4; ++it) xr[it] = xb4[gidx[it]];
    }
    __syncthreads();

    // ---- k-loop: pure LDS + MFMA, B from registers ----
    f32x4 acc[2][2];
#pragma unroll
    for (int i = 0; i < 2; ++i)
#pragma unroll
      for (int jj = 0; jj < 2; ++jj) acc[i][jj] = (f32x4){0.f, 0.f, 0.f, 0.f};

#pragma unroll
    for (int k = 0; k < 8; ++k) {
      bf16x8 Ah0 = *(const bf16x8*)(&xs_h[buf][((k * 2 + 0) * 64 + l) * 8]);
      bf16x8 Ah1 = *(const bf16x8*)(&xs_h[buf][((k * 2 + 1) * 64 + l) * 8]);
      bf16x8 Al0 = *(const bf16x8*)(&xs_l[buf][((k * 2 + 0) * 64 + l) * 8]);
      bf16x8 Al1 = *(const bf16x8*)(&xs_l[buf][((k * 2 + 1) * 64 + l) * 8]);
#pragma unroll
      for (int jj = 0; jj < 2; ++jj) {
        acc[0][jj] = __builtin_amdgcn_mfma_f32_16x16x32_bf16(Ah0, Bh[k][jj], acc[0][jj], 0, 0, 0);
        acc[1][jj] = __builtin_amdgcn_mfma_f32_16x16x32_bf16(Ah1, Bh[k][jj], acc[1][jj], 0, 0, 0);
        acc[0][jj] = __builtin_amdgcn_mfma_f32_16x16x32_bf16(Ah0, Bl[k][jj], acc[0][jj], 0, 0, 0);
        acc[0][jj] = __builtin_amdgcn_mfma_f32_16x16x32_bf16(Al0, Bh[k][jj], acc[0][jj], 0, 0, 0);
        acc[1][jj] = __builtin_amdgcn_mfma_f32_16x16x32_bf16(Ah1, Bl[k][jj], acc[1][jj], 0, 0, 0);
        acc[1][jj] = __builtin_amdgcn_mfma_f32_16x16x32_bf16(Al1, Bh[k][jj], acc[1][jj], 0, 0, 0);
      }
    }

    // ---- per-token top-2 over this wave's 32 slots ----
    // C/D layout: col(slot) = l&15, row(token) = (l>>4)*4 + reg
#pragma unroll
    for (int i = 0; i < 2; ++i) {
#pragma unroll
      for (int rr = 0; rr < 4; ++rr) {
        float m1 = acc[i][0][rr];
        int   i1 = w * 32 + s15;
        float m2 = acc[i][1][rr];
        {
          float v = acc[i][1][rr];
          int   s = w * 32 + 16 + s15;
          if (v > m1) { m2 = m1; m1 = v; i1 = s; }
        }
#pragma unroll
        for (int off = 1; off < 16; off <<= 1) {
          float om1 = __shfl_xor(m1, off, 64);
          int   oi1 = __shfl_xor(i1, off, 64);
          float om2 = __shfl_xor(m2, off, 64);
          if (om1 > m1 || (om1 == m1 && oi1 < i1)) { m2 = fmaxf(m1, om2); m1 = om1; i1 = oi1; }
          else { m2 = fmaxf(m2, om1); }
        }
        if (s15 == 0) {
          int t = i * 16 + g4 * 4 + rr;
          rm1[w][t] = m1; rm2[w][t] = m2; ri1[w][t] = i1;
        }
      }
    }
    __syncthreads();

    // ---- cross-wave merge (ascending slot ranges -> first-index tie-break) ----
    if (tid < TOK) {
      float m1 = rm1[0][tid]; int i1 = ri1[0][tid]; float m2 = rm2[0][tid];
#pragma unroll
      for (int ww = 1; ww < 8; ++ww) {
        float om1 = rm1[ww][tid]; int oi1 = ri1[ww][tid]; float om2 = rm2[ww][tid];
        if (om1 > m1) { m2 = fmaxf(m1, om2); m1 = om1; i1 = oi1; }
        else { m2 = fmaxf(m2, om1); }
      }
      idx_s[tid] = i1;
      if (m1 - m2 <= MARGIN) {   // ambiguous under split-bf16 error -> f32 recheck
        unsigned pos = atomicAdd(cnt, 1u);
        if (pos < CAP) list[pos] = (((unsigned)(b * NN + n0 + tid)) << 8) | (unsigned)i1;
      }
    }
    __syncthreads();

    // ---- one-hot write ----
    float4* hbase = (float4*)(hard + ((size_t)b * NN + n0) * NQQ);
#pragma unroll
    for (int it = 0; it < 4; ++it) {
      int u = it * 512 + tid;
      int tk = u >> 6;
      int s0 = (u & 63) * 4;
      int tgt = idx_s[tk];
      float4 h;
      h.x = (s0 + 0 == tgt) ? 1.f : 0.f;
      h.y = (s0 + 1 == tgt) ? 1.f : 0.f;
      h.z = (s0 + 2 == tgt) ? 1.f : 0.f;
      h.w = (s0 + 3 == tgt) ? 1.f : 0.f;
      hbase[u] = h;
    }

    // ---- scatter from register copy: S[b, idx[tok], d0..d0+3] += x ----
    float* Sb = S + (size_t)b * NQQ * DMODEL;
#pragma unroll
    for (int it = 0; it < 4; ++it) {
      int tok = it * 8 + sc_tok_base;
      int tgt = idx_s[tok];
      float* p = Sb + (size_t)tgt * DMODEL + sc_d0;
      atomicAdd(p + 0, xr2[it].x);
      atomicAdd(p + 1, xr2[it].y);
      atomicAdd(p + 2, xr2[it].z);
      atomicAdd(p + 3, xr2[it].w);
    }
  }
}

// recheck: exact-f32 scores for ambiguous tokens; patch one-hot + S on flip
__global__ __launch_bounds__(256) void recheck_kernel(
    const float* __restrict__ x, const float* __restrict__ qk,
    const unsigned* __restrict__ cnt, const unsigned* __restrict__ list,
    float* __restrict__ S, float* __restrict__ hard) {
  __shared__ float xrow[DMODEL];
  __shared__ float sv[NQQ];
  __shared__ int   si[NQQ];
  const int tid = threadIdx.x;
  unsigned nc = cnt[0];
  int nA = (int)(nc < (unsigned)CAP ? nc : (unsigned)CAP);
  for (int e = blockIdx.x; e < nA; e += gridDim.x) {
    unsigned pk = list[e];
    int tokid = (int)(pk >> 8);
    int olds  = (int)(pk & 255u);
    const float* xr = x + (size_t)tokid * DMODEL;
    xrow[tid] = xr[tid];
    __syncthreads();
    const float* qr = qk + (size_t)tid * DMODEL;
    float a = 0.f;
#pragma unroll
    for (int d4 = 0; d4 < 64; ++d4) {   // strict sequential-d order (matches exact path)
      float4 qv = *(const float4*)(qr + d4 * 4);
      float4 xv = *(const float4*)(&xrow[d4 * 4]);
      a = fmaf(xv.x, qv.x, a); a = fmaf(xv.y, qv.y, a);
      a = fmaf(xv.z, qv.z, a); a = fmaf(xv.w, qv.w, a);
    }
    sv[tid] = a; si[tid] = tid;
    __syncthreads();
    for (int s = 128; s >= 1; s >>= 1) {
      if (tid < s) {
        float vo = sv[tid + s]; int io = si[tid + s];
        if (vo > sv[tid] || (vo == sv[tid] && io < si[tid])) { sv[tid] = vo; si[tid] = io; }
      }
      __syncthreads();
    }
    int news = si[0];
    if (news != olds) {
      int bb = tokid >> 13;
      if (tid == 0) {
        hard[(size_t)tokid * NQQ + olds] = 0.f;
        hard[(size_t)tokid * NQQ + news] = 1.f;
      }
      float xv = xrow[tid];
      atomicAdd(&S[((size_t)bb * NQQ + olds) * DMODEL + tid], -xv);
      atomicAdd(&S[((size_t)bb * NQQ + news) * DMODEL + tid],  xv);
    }
    __syncthreads();
  }
}

// out[b,s,d] = sum_dm S[b,s,dm] * MT[dm,d]
__global__ __launch_bounds__(256) void out_kernel(
    const float* __restrict__ S, const float* __restrict__ MT,
    float* __restrict__ out) {
  __shared__ float srow[8][DMODEL];
  const int tid = threadIdx.x;
  const int r0 = blockIdx.x * 8;
#pragma unroll
  for (int i = 0; i < 8; ++i) srow[i][tid] = S[(size_t)(r0 + i) * DMODEL + tid];
  __syncthreads();
  float a[8];
#pragma unroll
  for (int i = 0; i < 8; ++i) a[i] = 0.f;
  for (int dm = 0; dm < DMODEL; ++dm) {
    float m = MT[(size_t)dm * DMODEL + tid];
#pragma unroll
    for (int i = 0; i < 8; ++i) a[i] = fmaf(srow[i][dm], m, a[i]);
  }
#pragma unroll
  for (int i = 0; i < 8; ++i) out[(size_t)(r0 + i) * DMODEL + tid] = a[i];
}

extern "C" void kernel_launch(void* const* d_in, const int* in_sizes, int n_in,
                              void* d_out, int out_size, void* d_ws, size_t ws_size,
                              hipStream_t stream) {
  const float* x   = (const float*)d_in[0];
  const float* q   = (const float*)d_in[1];
  const float* wks = (const float*)d_in[2];
  const float* wvs = (const float*)d_in[3];
  const float* wfc = (const float*)d_in[4];

  float* out  = (float*)d_out;                       // (16,256,256)
  float* hard = out + (size_t)BB * NQQ * DMODEL;     // (16,8192,256)

  float* qk = (float*)d_ws;                          // 65536 f
  float* MT = qk + 65536;                            // 65536 f
  float* S  = MT + 65536;                            // 1048576 f (4 MB)
  unsigned* cnt  = (unsigned*)(S + 1048576);         // 64 u32 (pad)
  unsigned* list = cnt + 64;                         // CAP u32
  unsigned short* qhf = (unsigned short*)(list + CAP);  // 65536 bf16
  unsigned short* qlf = qhf + 65536;                    // 65536 bf16

  hipMemsetAsync(S, 0, (size_t)1048576 * sizeof(float), stream);
  hipMemsetAsync(cnt, 0, 256, stream);
  prep_kernel<<<2 * NQQ, 256, 0, stream>>>(q, wks, wvs, wfc, qk, MT, qhf, qlf);
  score_kernel<<<GRID, 512, 0, stream>>>(x, qhf, qlf, S, hard, cnt, list);
  recheck_kernel<<<2048, 256, 0, stream>>>(x, qk, cnt, list, S, hard);
  out_kernel<<<(BB * NQQ) / 8, 256, 0, stream>>>(S, MT, out);
}

// Round 7
// 368.315 us; speedup vs baseline: 1.5211x; 1.5211x over previous
//
#include <hip/hip_runtime.h>

#define BB 16
#define NN 8192
#define DMODEL 256
#define DKK 64
#define DVV 64
#define NQQ 256
#define TOK 32
#define MARGIN 0.02f
#define CAP 32768

typedef __attribute__((ext_vector_type(8))) short bf16x8;
typedef __attribute__((ext_vector_type(4))) float f32x4;

// RNE split of f32 into bf16 hi + bf16 lo (x ~= hi + lo, |err| ~ 2^-17 |x|)
__device__ __forceinline__ void split_bf16(float v, unsigned short& h, unsigned short& lo) {
  unsigned u = __float_as_uint(v);
  unsigned hr = (u + 0x7FFFu + ((u >> 16) & 1u)) & 0xFFFF0000u;
  h = (unsigned short)(hr >> 16);
  float r = v - __uint_as_float(hr);
  unsigned ul = __float_as_uint(r);
  lo = (unsigned short)((ul + 0x7FFFu + ((ul >> 16) & 1u)) >> 16);
}

// prep: qk = q @ w_ks (f32, for recheck), split-fragments qhf/qlf, MT = (w_fc @ w_vs)^T
__global__ __launch_bounds__(256) void prep_kernel(
    const float* __restrict__ q, const float* __restrict__ w_ks,
    const float* __restrict__ w_vs, const float* __restrict__ w_fc,
    float* __restrict__ qk, float* __restrict__ MT,
    unsigned short* __restrict__ qhf, unsigned short* __restrict__ qlf) {
  __shared__ float sbuf[DKK];
  const int tid = threadIdx.x;
  const int blk = blockIdx.x;
  if (blk < NQQ) {
    const int s = blk;
    if (tid < DKK) sbuf[tid] = q[s * DKK + tid];
    __syncthreads();
    float acc = 0.f;
#pragma unroll
    for (int k = 0; k < DKK; ++k) acc = fmaf(sbuf[k], w_ks[k * DMODEL + tid], acc);
    qk[s * DMODEL + tid] = acc;
    // B fragment layout: elem idx = ((kstep*16 + stile)*64 + (kg*16 + s15))*8 + jj
    int d = tid;
    int kstep = d >> 5, kg = (d >> 3) & 3, jj = d & 7;
    int stile = s >> 4, s15 = s & 15;
    int e = (((kstep * 16 + stile) * 64) + (kg * 16 + s15)) * 8 + jj;
    unsigned short hb, lb;
    split_bf16(acc, hb, lb);
    qhf[e] = hb; qlf[e] = lb;
  } else {
    const int dm = blk - NQQ;
    if (tid < DVV) sbuf[tid] = w_vs[tid * DMODEL + dm];
    __syncthreads();
    float acc = 0.f;
#pragma unroll
    for (int v = 0; v < DVV; ++v) acc = fmaf(w_fc[tid * DVV + v], sbuf[v], acc);
    MT[dm * DMODEL + tid] = acc;
  }
}

// main: split-bf16 MFMA scores, top-2 argmax + margin list, one-hot write, idx write.
// NO global atomics (the S scatter moved to reduce_kernel).
__global__ __launch_bounds__(256, 4) void score_kernel(
    const float* __restrict__ x, const unsigned short* __restrict__ qhf,
    const unsigned short* __restrict__ qlf,
    float* __restrict__ hard, unsigned char* __restrict__ idxa,
    unsigned* __restrict__ cnt, unsigned* __restrict__ list) {
  __shared__ unsigned short xs_h[8192];   // [kstep(8)][tile(2)][lane(64)][8] bf16, 16 KB
  __shared__ unsigned short xs_l[8192];   // 16 KB
  __shared__ float rm1[4][TOK];
  __shared__ float rm2[4][TOK];
  __shared__ int   ri1[4][TOK];
  __shared__ int   idx_s[TOK];

  const int tid = threadIdx.x;
  const int w = tid >> 6;       // wave 0..3 -> slot range w*64..w*64+63
  const int l = tid & 63;       // lane
  const int b = blockIdx.y;
  const int n0 = blockIdx.x * TOK;
  const float* xbase = x + ((size_t)b * NN + n0) * DMODEL;
  const float4* xb4 = (const float4*)xbase;

  // ---- stage x tile (32 tok x 256 d) as bf16 hi/lo fragments ----
  {
    const int tok = w * 8 + (l >> 3);          // 32 tokens
    const int r   = l & 7;
    const int kg  = r >> 1;                    // (c4>>1)&3
    const int j0  = (r & 1) * 4;
    const int i   = tok >> 4;
    const int t15 = tok & 15;
#pragma unroll
    for (int it = 0; it < 8; ++it) {
      int c4 = it * 8 + r;                     // kstep = it
      float4 v = xb4[tok * 64 + c4];
      int e = (((it * 2 + i) * 64) + (kg * 16 + t15)) * 8 + j0;
      ushort4 hh, ll;
      split_bf16(v.x, hh.x, ll.x);
      split_bf16(v.y, hh.y, ll.y);
      split_bf16(v.z, hh.z, ll.z);
      split_bf16(v.w, hh.w, ll.w);
      *(ushort4*)(&xs_h[e]) = hh;
      *(ushort4*)(&xs_l[e]) = ll;
    }
  }
  __syncthreads();

  // ---- MFMA: 32 tok x 64 slots per wave; acc[tile][stile] ----
  const bf16x8* bh = (const bf16x8*)qhf;
  const bf16x8* bl = (const bf16x8*)qlf;
  f32x4 acc[2][4];
#pragma unroll
  for (int i = 0; i < 2; ++i)
#pragma unroll
    for (int j = 0; j < 4; ++j) acc[i][j] = (f32x4){0.f, 0.f, 0.f, 0.f};

#pragma unroll
  for (int k = 0; k < 8; ++k) {
    bf16x8 Bh[4], Bl[4], Ah[2], Al[2];
#pragma unroll
    for (int j = 0; j < 4; ++j) {
      Bh[j] = bh[(k * 16 + w * 4 + j) * 64 + l];   // L2-resident global, lane-contig
      Bl[j] = bl[(k * 16 + w * 4 + j) * 64 + l];
    }
#pragma unroll
    for (int i = 0; i < 2; ++i) {
      Ah[i] = *(const bf16x8*)(&xs_h[((k * 2 + i) * 64 + l) * 8]);  // conflict-free b128
      Al[i] = *(const bf16x8*)(&xs_l[((k * 2 + i) * 64 + l) * 8]);
    }
#pragma unroll
    for (int i = 0; i < 2; ++i)
#pragma unroll
      for (int j = 0; j < 4; ++j) {
        acc[i][j] = __builtin_amdgcn_mfma_f32_16x16x32_bf16(Ah[i], Bh[j], acc[i][j], 0, 0, 0);
        acc[i][j] = __builtin_amdgcn_mfma_f32_16x16x32_bf16(Ah[i], Bl[j], acc[i][j], 0, 0, 0);
        acc[i][j] = __builtin_amdgcn_mfma_f32_16x16x32_bf16(Al[i], Bh[j], acc[i][j], 0, 0, 0);
      }
  }

  // ---- per-token top-2 over this wave's 64 slots ----
  // C/D layout: col(slot) = l&15, row(token) = (l>>4)*4 + reg
  const int s15 = l & 15, g4 = l >> 4;
#pragma unroll
  for (int i = 0; i < 2; ++i) {
#pragma unroll
    for (int rr = 0; rr < 4; ++rr) {
      float m1 = acc[i][0][rr];
      int   i1 = w * 64 + s15;
      float m2 = -1e30f;
#pragma unroll
      for (int j = 1; j < 4; ++j) {
        float v = acc[i][j][rr];
        int   s = w * 64 + j * 16 + s15;
        if (v > m1) { m2 = m1; m1 = v; i1 = s; }
        else if (v > m2) m2 = v;
      }
#pragma unroll
      for (int off = 1; off < 16; off <<= 1) {
        float om1 = __shfl_xor(m1, off, 64);
        int   oi1 = __shfl_xor(i1, off, 64);
        float om2 = __shfl_xor(m2, off, 64);
        if (om1 > m1 || (om1 == m1 && oi1 < i1)) { m2 = fmaxf(m1, om2); m1 = om1; i1 = oi1; }
        else { m2 = fmaxf(m2, om1); }
      }
      if (s15 == 0) {
        int t = i * 16 + g4 * 4 + rr;
        rm1[w][t] = m1; rm2[w][t] = m2; ri1[w][t] = i1;
      }
    }
  }
  __syncthreads();

  // ---- cross-wave merge (ascending slot ranges -> first-index tie-break) ----
  if (tid < TOK) {
    float m1 = rm1[0][tid]; int i1 = ri1[0][tid]; float m2 = rm2[0][tid];
#pragma unroll
    for (int ww = 1; ww < 4; ++ww) {
      float om1 = rm1[ww][tid]; int oi1 = ri1[ww][tid]; float om2 = rm2[ww][tid];
      if (om1 > m1) { m2 = fmaxf(m1, om2); m1 = om1; i1 = oi1; }
      else { m2 = fmaxf(m2, om1); }
    }
    idx_s[tid] = i1;
    idxa[(size_t)b * NN + n0 + tid] = (unsigned char)i1;
    if (m1 - m2 <= MARGIN) {   // ambiguous under split-bf16 error -> f32 recheck
      unsigned pos = atomicAdd(cnt, 1u);
      if (pos < CAP) list[pos] = (((unsigned)(b * NN + n0 + tid)) << 8) | (unsigned)i1;
    }
  }
  __syncthreads();

  // ---- one-hot write (provisional; recheck patches flagged tokens) ----
  float4* hbase = (float4*)(hard + ((size_t)b * NN + n0) * NQQ);
#pragma unroll
  for (int it = 0; it < 8; ++it) {
    int u = it * 256 + tid;
    int tk = u >> 6;
    int s0 = (u & 63) * 4;
    int tgt = idx_s[tk];
    float4 h;
    h.x = (s0 + 0 == tgt) ? 1.f : 0.f;
    h.y = (s0 + 1 == tgt) ? 1.f : 0.f;
    h.z = (s0 + 2 == tgt) ? 1.f : 0.f;
    h.w = (s0 + 3 == tgt) ? 1.f : 0.f;
    hbase[u] = h;
  }
}

// recheck: exact-f32 scores for ambiguous tokens; patch one-hot + idx byte on flip
__global__ __launch_bounds__(256) void recheck_kernel(
    const float* __restrict__ x, const float* __restrict__ qk,
    const unsigned* __restrict__ cnt, const unsigned* __restrict__ list,
    float* __restrict__ hard, unsigned char* __restrict__ idxa) {
  __shared__ float xrow[DMODEL];
  __shared__ float sv[NQQ];
  __shared__ int   si[NQQ];
  const int tid = threadIdx.x;
  unsigned nc = cnt[0];
  int nA = (int)(nc < (unsigned)CAP ? nc : (unsigned)CAP);
  for (int e = blockIdx.x; e < nA; e += gridDim.x) {
    unsigned pk = list[e];
    int tokid = (int)(pk >> 8);
    int olds  = (int)(pk & 255u);
    const float* xr = x + (size_t)tokid * DMODEL;
    xrow[tid] = xr[tid];
    __syncthreads();
    const float* qr = qk + (size_t)tid * DMODEL;
    float a = 0.f;
#pragma unroll
    for (int d4 = 0; d4 < 64; ++d4) {   // strict sequential-d order (matches exact path)
      float4 qv = *(const float4*)(qr + d4 * 4);
      float4 xv = *(const float4*)(&xrow[d4 * 4]);
      a = fmaf(xv.x, qv.x, a); a = fmaf(xv.y, qv.y, a);
      a = fmaf(xv.z, qv.z, a); a = fmaf(xv.w, qv.w, a);
    }
    sv[tid] = a; si[tid] = tid;
    __syncthreads();
    for (int s = 128; s >= 1; s >>= 1) {
      if (tid < s) {
        float vo = sv[tid + s]; int io = si[tid + s];
        if (vo > sv[tid] || (vo == sv[tid] && io < si[tid])) { sv[tid] = vo; si[tid] = io; }
      }
      __syncthreads();
    }
    int news = si[0];
    if (news != olds && tid == 0) {
      hard[(size_t)tokid * NQQ + olds] = 0.f;
      hard[(size_t)tokid * NQQ + news] = 1.f;
      idxa[tokid] = (unsigned char)news;
    }
    __syncthreads();
  }
}

// reduce: S[b, slot, :] = sum over tokens with idx==slot of x[b,n,:]
// block = (b, slot-group of 16); no atomics; exclusive S region per block.
__global__ __launch_bounds__(512) void reduce_kernel(
    const float* __restrict__ x, const unsigned char* __restrict__ idxa,
    float* __restrict__ S) {
  __shared__ unsigned char idx_l[NN];       // 8 KB
  __shared__ float accs[2][16][DMODEL];     // 32 KB
  const int tid = threadIdx.x;
  const int b  = blockIdx.x >> 4;
  const int sg = blockIdx.x & 15;
  const int h  = tid >> 8;                  // half: scans 4096 tokens
  const int d  = tid & 255;
  // stage idx bytes (512 x 16B)
  ((uint4*)idx_l)[tid] = ((const uint4*)(idxa + (size_t)b * NN))[tid];
  float* af = &accs[0][0][0];
#pragma unroll
  for (int i = 0; i < 16; ++i) af[i * 512 + tid] = 0.f;
  __syncthreads();

  const float* xb = x + (size_t)b * NN * DMODEL + d;
  float* myacc = &accs[h][0][0] + d;
  const int n0 = h * 4096;
  for (int n4 = 0; n4 < 1024; ++n4) {
    unsigned w4 = *(const unsigned*)(&idx_l[n0 + n4 * 4]);  // 4 idx bytes, broadcast
#pragma unroll
    for (int j = 0; j < 4; ++j) {
      int s = (w4 >> (8 * j)) & 255;
      if ((s >> 4) == sg) {   // wave-uniform branch
        int n = n0 + n4 * 4 + j;
        myacc[(s & 15) * DMODEL] += xb[(size_t)n * DMODEL];
      }
    }
  }
  __syncthreads();

  // write S (exclusive region): 16 rows x 256
#pragma unroll
  for (int i = 0; i < 8; ++i) {
    int u = i * 512 + tid;
    int ss = u >> 8, dd = u & 255;
    S[((size_t)b * NQQ + sg * 16 + ss) * DMODEL + dd] = accs[0][ss][dd] + accs[1][ss][dd];
  }
}

// out[b,s,d] = sum_dm S[b,s,dm] * MT[dm,d]
__global__ __launch_bounds__(256) void out_kernel(
    const float* __restrict__ S, const float* __restrict__ MT,
    float* __restrict__ out) {
  __shared__ float srow[8][DMODEL];
  const int tid = threadIdx.x;
  const int r0 = blockIdx.x * 8;
#pragma unroll
  for (int i = 0; i < 8; ++i) srow[i][tid] = S[(size_t)(r0 + i) * DMODEL + tid];
  __syncthreads();
  float a[8];
#pragma unroll
  for (int i = 0; i < 8; ++i) a[i] = 0.f;
  for (int dm = 0; dm < DMODEL; ++dm) {
    float m = MT[(size_t)dm * DMODEL + tid];
#pragma unroll
    for (int i = 0; i < 8; ++i) a[i] = fmaf(srow[i][dm], m, a[i]);
  }
#pragma unroll
  for (int i = 0; i < 8; ++i) out[(size_t)(r0 + i) * DMODEL + tid] = a[i];
}

extern "C" void kernel_launch(void* const* d_in, const int* in_sizes, int n_in,
                              void* d_out, int out_size, void* d_ws, size_t ws_size,
                              hipStream_t stream) {
  const float* x   = (const float*)d_in[0];
  const float* q   = (const float*)d_in[1];
  const float* wks = (const float*)d_in[2];
  const float* wvs = (const float*)d_in[3];
  const float* wfc = (const float*)d_in[4];

  float* out  = (float*)d_out;                       // (16,256,256)
  float* hard = out + (size_t)BB * NQQ * DMODEL;     // (16,8192,256)

  float* qk = (float*)d_ws;                          // 65536 f
  float* MT = qk + 65536;                            // 65536 f
  float* S  = MT + 65536;                            // 1048576 f (4 MB)
  unsigned* cnt  = (unsigned*)(S + 1048576);         // 64 u32 (pad)
  unsigned* list = cnt + 64;                         // CAP u32
  unsigned short* qhf = (unsigned short*)(list + CAP);   // 65536 bf16
  unsigned short* qlf = qhf + 65536;                     // 65536 bf16
  unsigned char*  idxa = (unsigned char*)(qlf + 65536);  // 131072 bytes

  hipMemsetAsync(cnt, 0, 256, stream);
  prep_kernel<<<2 * NQQ, 256, 0, stream>>>(q, wks, wvs, wfc, qk, MT, qhf, qlf);
  score_kernel<<<dim3(NN / TOK, BB), 256, 0, stream>>>(x, qhf, qlf, hard, idxa, cnt, list);
  recheck_kernel<<<2048, 256, 0, stream>>>(x, qk, cnt, list, hard, idxa);
  reduce_kernel<<<BB * 16, 512, 0, stream>>>(x, idxa, S);
  out_kernel<<<(BB * NQQ) / 8, 256, 0, stream>>>(S, MT, out);
}

// Round 8
// 186.510 us; speedup vs baseline: 3.0038x; 1.9748x over previous
//
#include <hip/hip_runtime.h>

#define BB 16
#define NN 8192
#define DMODEL 256
#define DKK 64
#define DVV 64
#define NQQ 256
#define TOK 32
#define MARGIN 0.02f
#define CAP 32768

typedef __attribute__((ext_vector_type(8))) short bf16x8;
typedef __attribute__((ext_vector_type(4))) float f32x4;

// RNE split of f32 into bf16 hi + bf16 lo (x ~= hi + lo, |err| ~ 2^-17 |x|)
__device__ __forceinline__ void split_bf16(float v, unsigned short& h, unsigned short& lo) {
  unsigned u = __float_as_uint(v);
  unsigned hr = (u + 0x7FFFu + ((u >> 16) & 1u)) & 0xFFFF0000u;
  h = (unsigned short)(hr >> 16);
  float r = v - __uint_as_float(hr);
  unsigned ul = __float_as_uint(r);
  lo = (unsigned short)((ul + 0x7FFFu + ((ul >> 16) & 1u)) >> 16);
}

// prep: qk = q @ w_ks (f32, for recheck), split-fragments qhf/qlf, MT = (w_fc @ w_vs)^T
__global__ __launch_bounds__(256) void prep_kernel(
    const float* __restrict__ q, const float* __restrict__ w_ks,
    const float* __restrict__ w_vs, const float* __restrict__ w_fc,
    float* __restrict__ qk, float* __restrict__ MT,
    unsigned short* __restrict__ qhf, unsigned short* __restrict__ qlf) {
  __shared__ float sbuf[DKK];
  const int tid = threadIdx.x;
  const int blk = blockIdx.x;
  if (blk < NQQ) {
    const int s = blk;
    if (tid < DKK) sbuf[tid] = q[s * DKK + tid];
    __syncthreads();
    float acc = 0.f;
#pragma unroll
    for (int k = 0; k < DKK; ++k) acc = fmaf(sbuf[k], w_ks[k * DMODEL + tid], acc);
    qk[s * DMODEL + tid] = acc;
    // B fragment layout: elem idx = ((kstep*16 + stile)*64 + (kg*16 + s15))*8 + jj
    int d = tid;
    int kstep = d >> 5, kg = (d >> 3) & 3, jj = d & 7;
    int stile = s >> 4, s15 = s & 15;
    int e = (((kstep * 16 + stile) * 64) + (kg * 16 + s15)) * 8 + jj;
    unsigned short hb, lb;
    split_bf16(acc, hb, lb);
    qhf[e] = hb; qlf[e] = lb;
  } else {
    const int dm = blk - NQQ;
    if (tid < DVV) sbuf[tid] = w_vs[tid * DMODEL + dm];
    __syncthreads();
    float acc = 0.f;
#pragma unroll
    for (int v = 0; v < DVV; ++v) acc = fmaf(w_fc[tid * DVV + v], sbuf[v], acc);
    MT[dm * DMODEL + tid] = acc;
  }
}

// main: split-bf16 MFMA scores, top-2 argmax + margin list, one-hot write, idx write.
__global__ __launch_bounds__(256, 4) void score_kernel(
    const float* __restrict__ x, const unsigned short* __restrict__ qhf,
    const unsigned short* __restrict__ qlf,
    float* __restrict__ hard, unsigned char* __restrict__ idxa,
    unsigned* __restrict__ cnt, unsigned* __restrict__ list) {
  __shared__ unsigned short xs_h[8192];   // [kstep(8)][tile(2)][lane(64)][8] bf16, 16 KB
  __shared__ unsigned short xs_l[8192];   // 16 KB
  __shared__ float rm1[4][TOK];
  __shared__ float rm2[4][TOK];
  __shared__ int   ri1[4][TOK];
  __shared__ int   idx_s[TOK];

  const int tid = threadIdx.x;
  const int w = tid >> 6;       // wave 0..3 -> slot range w*64..w*64+63
  const int l = tid & 63;       // lane
  const int b = blockIdx.y;
  const int n0 = blockIdx.x * TOK;
  const float* xbase = x + ((size_t)b * NN + n0) * DMODEL;
  const float4* xb4 = (const float4*)xbase;

  // ---- stage x tile (32 tok x 256 d) as bf16 hi/lo fragments ----
  {
    const int tok = w * 8 + (l >> 3);          // 32 tokens
    const int r   = l & 7;
    const int kg  = r >> 1;                    // (c4>>1)&3
    const int j0  = (r & 1) * 4;
    const int i   = tok >> 4;
    const int t15 = tok & 15;
#pragma unroll
    for (int it = 0; it < 8; ++it) {
      int c4 = it * 8 + r;                     // kstep = it
      float4 v = xb4[tok * 64 + c4];
      int e = (((it * 2 + i) * 64) + (kg * 16 + t15)) * 8 + j0;
      ushort4 hh, ll;
      split_bf16(v.x, hh.x, ll.x);
      split_bf16(v.y, hh.y, ll.y);
      split_bf16(v.z, hh.z, ll.z);
      split_bf16(v.w, hh.w, ll.w);
      *(ushort4*)(&xs_h[e]) = hh;
      *(ushort4*)(&xs_l[e]) = ll;
    }
  }
  __syncthreads();

  // ---- MFMA: 32 tok x 64 slots per wave; acc[tile][stile] ----
  const bf16x8* bh = (const bf16x8*)qhf;
  const bf16x8* bl = (const bf16x8*)qlf;
  f32x4 acc[2][4];
#pragma unroll
  for (int i = 0; i < 2; ++i)
#pragma unroll
    for (int j = 0; j < 4; ++j) acc[i][j] = (f32x4){0.f, 0.f, 0.f, 0.f};

#pragma unroll
  for (int k = 0; k < 8; ++k) {
    bf16x8 Bh[4], Bl[4], Ah[2], Al[2];
#pragma unroll
    for (int j = 0; j < 4; ++j) {
      Bh[j] = bh[(k * 16 + w * 4 + j) * 64 + l];   // L2-resident global, lane-contig
      Bl[j] = bl[(k * 16 + w * 4 + j) * 64 + l];
    }
#pragma unroll
    for (int i = 0; i < 2; ++i) {
      Ah[i] = *(const bf16x8*)(&xs_h[((k * 2 + i) * 64 + l) * 8]);  // conflict-free b128
      Al[i] = *(const bf16x8*)(&xs_l[((k * 2 + i) * 64 + l) * 8]);
    }
#pragma unroll
    for (int i = 0; i < 2; ++i)
#pragma unroll
      for (int j = 0; j < 4; ++j) {
        acc[i][j] = __builtin_amdgcn_mfma_f32_16x16x32_bf16(Ah[i], Bh[j], acc[i][j], 0, 0, 0);
        acc[i][j] = __builtin_amdgcn_mfma_f32_16x16x32_bf16(Ah[i], Bl[j], acc[i][j], 0, 0, 0);
        acc[i][j] = __builtin_amdgcn_mfma_f32_16x16x32_bf16(Al[i], Bh[j], acc[i][j], 0, 0, 0);
      }
  }

  // ---- per-token top-2 over this wave's 64 slots ----
  // C/D layout: col(slot) = l&15, row(token) = (l>>4)*4 + reg
  const int s15 = l & 15, g4 = l >> 4;
#pragma unroll
  for (int i = 0; i < 2; ++i) {
#pragma unroll
    for (int rr = 0; rr < 4; ++rr) {
      float m1 = acc[i][0][rr];
      int   i1 = w * 64 + s15;
      float m2 = -1e30f;
#pragma unroll
      for (int j = 1; j < 4; ++j) {
        float v = acc[i][j][rr];
        int   s = w * 64 + j * 16 + s15;
        if (v > m1) { m2 = m1; m1 = v; i1 = s; }
        else if (v > m2) m2 = v;
      }
#pragma unroll
      for (int off = 1; off < 16; off <<= 1) {
        float om1 = __shfl_xor(m1, off, 64);
        int   oi1 = __shfl_xor(i1, off, 64);
        float om2 = __shfl_xor(m2, off, 64);
        if (om1 > m1 || (om1 == m1 && oi1 < i1)) { m2 = fmaxf(m1, om2); m1 = om1; i1 = oi1; }
        else { m2 = fmaxf(m2, om1); }
      }
      if (s15 == 0) {
        int t = i * 16 + g4 * 4 + rr;
        rm1[w][t] = m1; rm2[w][t] = m2; ri1[w][t] = i1;
      }
    }
  }
  __syncthreads();

  // ---- cross-wave merge (ascending slot ranges -> first-index tie-break) ----
  if (tid < TOK) {
    float m1 = rm1[0][tid]; int i1 = ri1[0][tid]; float m2 = rm2[0][tid];
#pragma unroll
    for (int ww = 1; ww < 4; ++ww) {
      float om1 = rm1[ww][tid]; int oi1 = ri1[ww][tid]; float om2 = rm2[ww][tid];
      if (om1 > m1) { m2 = fmaxf(m1, om2); m1 = om1; i1 = oi1; }
      else { m2 = fmaxf(m2, om1); }
    }
    idx_s[tid] = i1;
    idxa[(size_t)b * NN + n0 + tid] = (unsigned char)i1;
    if (m1 - m2 <= MARGIN) {   // ambiguous under split-bf16 error -> f32 recheck
      unsigned pos = atomicAdd(cnt, 1u);
      if (pos < CAP) list[pos] = (((unsigned)(b * NN + n0 + tid)) << 8) | (unsigned)i1;
    }
  }
  __syncthreads();

  // ---- one-hot write (provisional; recheck patches flagged tokens) ----
  float4* hbase = (float4*)(hard + ((size_t)b * NN + n0) * NQQ);
#pragma unroll
  for (int it = 0; it < 8; ++it) {
    int u = it * 256 + tid;
    int tk = u >> 6;
    int s0 = (u & 63) * 4;
    int tgt = idx_s[tk];
    float4 h;
    h.x = (s0 + 0 == tgt) ? 1.f : 0.f;
    h.y = (s0 + 1 == tgt) ? 1.f : 0.f;
    h.z = (s0 + 2 == tgt) ? 1.f : 0.f;
    h.w = (s0 + 3 == tgt) ? 1.f : 0.f;
    hbase[u] = h;
  }
}

// recheck: exact-f32 scores for ambiguous tokens; patch one-hot + idx byte on flip
__global__ __launch_bounds__(256) void recheck_kernel(
    const float* __restrict__ x, const float* __restrict__ qk,
    const unsigned* __restrict__ cnt, const unsigned* __restrict__ list,
    float* __restrict__ hard, unsigned char* __restrict__ idxa) {
  __shared__ float xrow[DMODEL];
  __shared__ float sv[NQQ];
  __shared__ int   si[NQQ];
  const int tid = threadIdx.x;
  unsigned nc = cnt[0];
  int nA = (int)(nc < (unsigned)CAP ? nc : (unsigned)CAP);
  for (int e = blockIdx.x; e < nA; e += gridDim.x) {
    unsigned pk = list[e];
    int tokid = (int)(pk >> 8);
    int olds  = (int)(pk & 255u);
    const float* xr = x + (size_t)tokid * DMODEL;
    xrow[tid] = xr[tid];
    __syncthreads();
    const float* qr = qk + (size_t)tid * DMODEL;
    float a = 0.f;
#pragma unroll
    for (int d4 = 0; d4 < 64; ++d4) {   // strict sequential-d order (matches exact path)
      float4 qv = *(const float4*)(qr + d4 * 4);
      float4 xv = *(const float4*)(&xrow[d4 * 4]);
      a = fmaf(xv.x, qv.x, a); a = fmaf(xv.y, qv.y, a);
      a = fmaf(xv.z, qv.z, a); a = fmaf(xv.w, qv.w, a);
    }
    sv[tid] = a; si[tid] = tid;
    __syncthreads();
    for (int s = 128; s >= 1; s >>= 1) {
      if (tid < s) {
        float vo = sv[tid + s]; int io = si[tid + s];
        if (vo > sv[tid] || (vo == sv[tid] && io < si[tid])) { sv[tid] = vo; si[tid] = io; }
      }
      __syncthreads();
    }
    int news = si[0];
    if (news != olds && tid == 0) {
      hard[(size_t)tokid * NQQ + olds] = 0.f;
      hard[(size_t)tokid * NQQ + news] = 1.f;
      idxa[tokid] = (unsigned char)news;
    }
    __syncthreads();
  }
}

// reduce v2: compact-then-process. S[b, slot, :] = sum of x rows whose idx==slot.
// block = (b, slot-group of 16); no global atomics; exclusive S region per block.
__global__ __launch_bounds__(512) void reduce_kernel(
    const float* __restrict__ x, const unsigned char* __restrict__ idxa,
    float* __restrict__ S) {
  __shared__ unsigned char  idx_l[NN];        // 8 KB
  __shared__ unsigned short list_l[NN];       // 16 KB (worst-case all tokens one sg)
  __shared__ float accs[2][16][DMODEL];       // 32 KB
  __shared__ unsigned lcnt;
  const int tid = threadIdx.x;
  const int b  = blockIdx.x >> 4;
  const int sg = blockIdx.x & 15;
  const int h  = tid >> 8;                    // half
  const int d  = tid & 255;

  // stage idx bytes (512 x 16B) and keep own 16 bytes in regs
  uint4 myidx = ((const uint4*)(idxa + (size_t)b * NN))[tid];
  ((uint4*)idx_l)[tid] = myidx;
  float* af = &accs[0][0][0];
#pragma unroll
  for (int i = 0; i < 16; ++i) af[i * 512 + tid] = 0.f;
  if (tid == 0) lcnt = 0u;
  __syncthreads();

  // ---- phase 1: parallel compaction of matching token ids ----
  {
    unsigned base = (unsigned)tid * 16u;
    unsigned words[4] = {myidx.x, myidx.y, myidx.z, myidx.w};
#pragma unroll
    for (int wi = 0; wi < 4; ++wi)
#pragma unroll
      for (int j = 0; j < 4; ++j) {
        int s = (words[wi] >> (8 * j)) & 255;
        if ((s >> 4) == sg) {
          unsigned pos = atomicAdd(&lcnt, 1u);
          list_l[pos] = (unsigned short)(base + wi * 4 + j);
        }
      }
  }
  __syncthreads();

  // ---- phase 2: process compacted list, 4-wide load pipeline ----
  const int cnt_ = (int)lcnt;
  const float* xb = x + (size_t)b * NN * DMODEL + d;
  float* myacc = &accs[h][0][0] + d;
  int start = (h * cnt_) >> 1;
  int end   = ((h + 1) * cnt_) >> 1;
  int i = start;
  for (; i + 4 <= end; i += 4) {
    int na = list_l[i], nb = list_l[i + 1], nc = list_l[i + 2], nd = list_l[i + 3];
    float va = xb[(size_t)na * DMODEL];
    float vb = xb[(size_t)nb * DMODEL];
    float vc = xb[(size_t)nc * DMODEL];
    float vd = xb[(size_t)nd * DMODEL];
    myacc[(idx_l[na] & 15) * DMODEL] += va;
    myacc[(idx_l[nb] & 15) * DMODEL] += vb;
    myacc[(idx_l[nc] & 15) * DMODEL] += vc;
    myacc[(idx_l[nd] & 15) * DMODEL] += vd;
  }
  for (; i < end; ++i) {
    int n = list_l[i];
    myacc[(idx_l[n] & 15) * DMODEL] += xb[(size_t)n * DMODEL];
  }
  __syncthreads();

  // ---- write S (exclusive region): 16 rows x 256 ----
#pragma unroll
  for (int ii = 0; ii < 8; ++ii) {
    int u = ii * 512 + tid;
    int ss = u >> 8, dd = u & 255;
    S[((size_t)b * NQQ + sg * 16 + ss) * DMODEL + dd] = accs[0][ss][dd] + accs[1][ss][dd];
  }
}

// out[b,s,d] = sum_dm S[b,s,dm] * MT[dm,d]
__global__ __launch_bounds__(256) void out_kernel(
    const float* __restrict__ S, const float* __restrict__ MT,
    float* __restrict__ out) {
  __shared__ float srow[8][DMODEL];
  const int tid = threadIdx.x;
  const int r0 = blockIdx.x * 8;
#pragma unroll
  for (int i = 0; i < 8; ++i) srow[i][tid] = S[(size_t)(r0 + i) * DMODEL + tid];
  __syncthreads();
  float a[8];
#pragma unroll
  for (int i = 0; i < 8; ++i) a[i] = 0.f;
  for (int dm = 0; dm < DMODEL; ++dm) {
    float m = MT[(size_t)dm * DMODEL + tid];
#pragma unroll
    for (int i = 0; i < 8; ++i) a[i] = fmaf(srow[i][dm], m, a[i]);
  }
#pragma unroll
  for (int i = 0; i < 8; ++i) out[(size_t)(r0 + i) * DMODEL + tid] = a[i];
}

extern "C" void kernel_launch(void* const* d_in, const int* in_sizes, int n_in,
                              void* d_out, int out_size, void* d_ws, size_t ws_size,
                              hipStream_t stream) {
  const float* x   = (const float*)d_in[0];
  const float* q   = (const float*)d_in[1];
  const float* wks = (const float*)d_in[2];
  const float* wvs = (const float*)d_in[3];
  const float* wfc = (const float*)d_in[4];

  float* out  = (float*)d_out;                       // (16,256,256)
  float* hard = out + (size_t)BB * NQQ * DMODEL;     // (16,8192,256)

  float* qk = (float*)d_ws;                          // 65536 f
  float* MT = qk + 65536;                            // 65536 f
  float* S  = MT + 65536;                            // 1048576 f (4 MB)
  unsigned* cnt  = (unsigned*)(S + 1048576);         // 64 u32 (pad)
  unsigned* list = cnt + 64;                         // CAP u32
  unsigned short* qhf = (unsigned short*)(list + CAP);   // 65536 bf16
  unsigned short* qlf = qhf + 65536;                     // 65536 bf16
  unsigned char*  idxa = (unsigned char*)(qlf + 65536);  // 131072 bytes

  hipMemsetAsync(cnt, 0, 256, stream);
  prep_kernel<<<2 * NQQ, 256, 0, stream>>>(q, wks, wvs, wfc, qk, MT, qhf, qlf);
  score_kernel<<<dim3(NN / TOK, BB), 256, 0, stream>>>(x, qhf, qlf, hard, idxa, cnt, list);
  recheck_kernel<<<2048, 256, 0, stream>>>(x, qk, cnt, list, hard, idxa);
  reduce_kernel<<<BB * 16, 512, 0, stream>>>(x, idxa, S);
  out_kernel<<<(BB * NQQ) / 8, 256, 0, stream>>>(S, MT, out);
}

// Round 9
// 185.760 us; speedup vs baseline: 3.0159x; 1.0040x over previous
//
#include <hip/hip_runtime.h>

#define BB 16
#define NN 8192
#define DMODEL 256
#define DKK 64
#define DVV 64
#define NQQ 256
#define TOK 32
#define MARGIN 0.02f
#define CAP 32768

typedef __attribute__((ext_vector_type(8))) short bf16x8;
typedef __attribute__((ext_vector_type(4))) float f32x4;

// RNE split of f32 into bf16 hi + bf16 lo (x ~= hi + lo, |err| ~ 2^-17 |x|)
__device__ __forceinline__ void split_bf16(float v, unsigned short& h, unsigned short& lo) {
  unsigned u = __float_as_uint(v);
  unsigned hr = (u + 0x7FFFu + ((u >> 16) & 1u)) & 0xFFFF0000u;
  h = (unsigned short)(hr >> 16);
  float r = v - __uint_as_float(hr);
  unsigned ul = __float_as_uint(r);
  lo = (unsigned short)((ul + 0x7FFFu + ((ul >> 16) & 1u)) >> 16);
}

// prep: qk = q @ w_ks (f32, for recheck), split-fragments qhf/qlf, MT = (w_fc @ w_vs)^T
__global__ __launch_bounds__(256) void prep_kernel(
    const float* __restrict__ q, const float* __restrict__ w_ks,
    const float* __restrict__ w_vs, const float* __restrict__ w_fc,
    float* __restrict__ qk, float* __restrict__ MT,
    unsigned short* __restrict__ qhf, unsigned short* __restrict__ qlf) {
  __shared__ float sbuf[DKK];
  const int tid = threadIdx.x;
  const int blk = blockIdx.x;
  if (blk < NQQ) {
    const int s = blk;
    if (tid < DKK) sbuf[tid] = q[s * DKK + tid];
    __syncthreads();
    float acc = 0.f;
#pragma unroll
    for (int k = 0; k < DKK; ++k) acc = fmaf(sbuf[k], w_ks[k * DMODEL + tid], acc);
    qk[s * DMODEL + tid] = acc;
    // B fragment layout: elem idx = ((kstep*16 + stile)*64 + (kg*16 + s15))*8 + jj
    int d = tid;
    int kstep = d >> 5, kg = (d >> 3) & 3, jj = d & 7;
    int stile = s >> 4, s15 = s & 15;
    int e = (((kstep * 16 + stile) * 64) + (kg * 16 + s15)) * 8 + jj;
    unsigned short hb, lb;
    split_bf16(acc, hb, lb);
    qhf[e] = hb; qlf[e] = lb;
  } else {
    const int dm = blk - NQQ;
    if (tid < DVV) sbuf[tid] = w_vs[tid * DMODEL + dm];
    __syncthreads();
    float acc = 0.f;
#pragma unroll
    for (int v = 0; v < DVV; ++v) acc = fmaf(w_fc[tid * DVV + v], sbuf[v], acc);
    MT[dm * DMODEL + tid] = acc;
  }
}

// one k-step: (optionally) prefetch B for k+1 into the other buffer, then 24 MFMAs
#define KSTEP(kk, Bhc, Blc, Bhn, Bln, PRE)                                              \
  {                                                                                     \
    if (PRE) {                                                                          \
      _Pragma("unroll")                                                                 \
      for (int j = 0; j < 4; ++j) {                                                     \
        Bhn[j] = bh[(((kk) + 1) * 16 + w * 4 + j) * 64 + l];                            \
        Bln[j] = bl[(((kk) + 1) * 16 + w * 4 + j) * 64 + l];                            \
      }                                                                                 \
    }                                                                                   \
    _Pragma("unroll")                                                                   \
    for (int i = 0; i < 2; ++i) {                                                       \
      bf16x8 Ah = *(const bf16x8*)(&xs_h[(((kk) * 2 + i) * 64 + l) * 8]);               \
      bf16x8 Al = *(const bf16x8*)(&xs_l[(((kk) * 2 + i) * 64 + l) * 8]);               \
      _Pragma("unroll")                                                                 \
      for (int j = 0; j < 4; ++j) {                                                     \
        acc[i][j] = __builtin_amdgcn_mfma_f32_16x16x32_bf16(Ah, Bhc[j], acc[i][j], 0, 0, 0); \
        acc[i][j] = __builtin_amdgcn_mfma_f32_16x16x32_bf16(Ah, Blc[j], acc[i][j], 0, 0, 0); \
        acc[i][j] = __builtin_amdgcn_mfma_f32_16x16x32_bf16(Al, Bhc[j], acc[i][j], 0, 0, 0); \
      }                                                                                 \
    }                                                                                   \
  }

// main: split-bf16 MFMA scores (B reg-double-buffered), top-2 argmax + margin list,
// one-hot write, idx write. No global atomics except the tiny margin-list append.
__global__ __launch_bounds__(256, 4) void score_kernel(
    const float* __restrict__ x, const unsigned short* __restrict__ qhf,
    const unsigned short* __restrict__ qlf,
    float* __restrict__ hard, unsigned char* __restrict__ idxa,
    unsigned* __restrict__ cnt, unsigned* __restrict__ list) {
  __shared__ unsigned short xs_h[8192];   // [kstep(8)][tile(2)][lane(64)][8] bf16, 16 KB
  __shared__ unsigned short xs_l[8192];   // 16 KB
  __shared__ float rm1[4][TOK];
  __shared__ float rm2[4][TOK];
  __shared__ int   ri1[4][TOK];
  __shared__ int   idx_s[TOK];

  const int tid = threadIdx.x;
  const int w = tid >> 6;       // wave 0..3 -> slot range w*64..w*64+63
  const int l = tid & 63;       // lane
  const int b = blockIdx.y;
  const int n0 = blockIdx.x * TOK;
  const float* xbase = x + ((size_t)b * NN + n0) * DMODEL;
  const float4* xb4 = (const float4*)xbase;

  // ---- stage x tile (32 tok x 256 d) as bf16 hi/lo fragments ----
  {
    const int tok = w * 8 + (l >> 3);          // 32 tokens
    const int r   = l & 7;
    const int kg  = r >> 1;                    // (c4>>1)&3
    const int j0  = (r & 1) * 4;
    const int i   = tok >> 4;
    const int t15 = tok & 15;
#pragma unroll
    for (int it = 0; it < 8; ++it) {
      int c4 = it * 8 + r;                     // kstep = it
      float4 v = xb4[tok * 64 + c4];
      int e = (((it * 2 + i) * 64) + (kg * 16 + t15)) * 8 + j0;
      ushort4 hh, ll;
      split_bf16(v.x, hh.x, ll.x);
      split_bf16(v.y, hh.y, ll.y);
      split_bf16(v.z, hh.z, ll.z);
      split_bf16(v.w, hh.w, ll.w);
      *(ushort4*)(&xs_h[e]) = hh;
      *(ushort4*)(&xs_l[e]) = ll;
    }
  }

  // ---- preload B fragments for k=0 (overlaps with staging latency) ----
  const bf16x8* bh = (const bf16x8*)qhf;
  const bf16x8* bl = (const bf16x8*)qlf;
  bf16x8 BhA[4], BlA[4], BhB[4], BlB[4];
#pragma unroll
  for (int j = 0; j < 4; ++j) {
    BhA[j] = bh[(w * 4 + j) * 64 + l];
    BlA[j] = bl[(w * 4 + j) * 64 + l];
  }
  __syncthreads();

  // ---- MFMA: 32 tok x 64 slots per wave; B reg ping-pong hides L2 latency ----
  f32x4 acc[2][4];
#pragma unroll
  for (int i = 0; i < 2; ++i)
#pragma unroll
    for (int j = 0; j < 4; ++j) acc[i][j] = (f32x4){0.f, 0.f, 0.f, 0.f};

  KSTEP(0, BhA, BlA, BhB, BlB, true)
  KSTEP(1, BhB, BlB, BhA, BlA, true)
  KSTEP(2, BhA, BlA, BhB, BlB, true)
  KSTEP(3, BhB, BlB, BhA, BlA, true)
  KSTEP(4, BhA, BlA, BhB, BlB, true)
  KSTEP(5, BhB, BlB, BhA, BlA, true)
  KSTEP(6, BhA, BlA, BhB, BlB, true)
  KSTEP(7, BhB, BlB, BhA, BlA, false)

  // ---- per-token top-2 over this wave's 64 slots ----
  // C/D layout: col(slot) = l&15, row(token) = (l>>4)*4 + reg
  const int s15 = l & 15, g4 = l >> 4;
#pragma unroll
  for (int i = 0; i < 2; ++i) {
#pragma unroll
    for (int rr = 0; rr < 4; ++rr) {
      float m1 = acc[i][0][rr];
      int   i1 = w * 64 + s15;
      float m2 = -1e30f;
#pragma unroll
      for (int j = 1; j < 4; ++j) {
        float v = acc[i][j][rr];
        int   s = w * 64 + j * 16 + s15;
        if (v > m1) { m2 = m1; m1 = v; i1 = s; }
        else if (v > m2) m2 = v;
      }
#pragma unroll
      for (int off = 1; off < 16; off <<= 1) {
        float om1 = __shfl_xor(m1, off, 64);
        int   oi1 = __shfl_xor(i1, off, 64);
        float om2 = __shfl_xor(m2, off, 64);
        if (om1 > m1 || (om1 == m1 && oi1 < i1)) { m2 = fmaxf(m1, om2); m1 = om1; i1 = oi1; }
        else { m2 = fmaxf(m2, om1); }
      }
      if (s15 == 0) {
        int t = i * 16 + g4 * 4 + rr;
        rm1[w][t] = m1; rm2[w][t] = m2; ri1[w][t] = i1;
      }
    }
  }
  __syncthreads();

  // ---- cross-wave merge (ascending slot ranges -> first-index tie-break) ----
  if (tid < TOK) {
    float m1 = rm1[0][tid]; int i1 = ri1[0][tid]; float m2 = rm2[0][tid];
#pragma unroll
    for (int ww = 1; ww < 4; ++ww) {
      float om1 = rm1[ww][tid]; int oi1 = ri1[ww][tid]; float om2 = rm2[ww][tid];
      if (om1 > m1) { m2 = fmaxf(m1, om2); m1 = om1; i1 = oi1; }
      else { m2 = fmaxf(m2, om1); }
    }
    idx_s[tid] = i1;
    idxa[(size_t)b * NN + n0 + tid] = (unsigned char)i1;
    if (m1 - m2 <= MARGIN) {   // ambiguous under split-bf16 error -> f32 recheck
      unsigned pos = atomicAdd(cnt, 1u);
      if (pos < CAP) list[pos] = (((unsigned)(b * NN + n0 + tid)) << 8) | (unsigned)i1;
    }
  }
  __syncthreads();

  // ---- one-hot write (provisional; recheck patches flagged tokens) ----
  float4* hbase = (float4*)(hard + ((size_t)b * NN + n0) * NQQ);
#pragma unroll
  for (int it = 0; it < 8; ++it) {
    int u = it * 256 + tid;
    int tk = u >> 6;
    int s0 = (u & 63) * 4;
    int tgt = idx_s[tk];
    float4 h;
    h.x = (s0 + 0 == tgt) ? 1.f : 0.f;
    h.y = (s0 + 1 == tgt) ? 1.f : 0.f;
    h.z = (s0 + 2 == tgt) ? 1.f : 0.f;
    h.w = (s0 + 3 == tgt) ? 1.f : 0.f;
    hbase[u] = h;
  }
}

// recheck: exact-f32 scores for ambiguous tokens; patch one-hot + idx byte on flip
__global__ __launch_bounds__(256) void recheck_kernel(
    const float* __restrict__ x, const float* __restrict__ qk,
    const unsigned* __restrict__ cnt, const unsigned* __restrict__ list,
    float* __restrict__ hard, unsigned char* __restrict__ idxa) {
  __shared__ float xrow[DMODEL];
  __shared__ float sv[NQQ];
  __shared__ int   si[NQQ];
  const int tid = threadIdx.x;
  unsigned nc = cnt[0];
  int nA = (int)(nc < (unsigned)CAP ? nc : (unsigned)CAP);
  for (int e = blockIdx.x; e < nA; e += gridDim.x) {
    unsigned pk = list[e];
    int tokid = (int)(pk >> 8);
    int olds  = (int)(pk & 255u);
    const float* xr = x + (size_t)tokid * DMODEL;
    xrow[tid] = xr[tid];
    __syncthreads();
    const float* qr = qk + (size_t)tid * DMODEL;
    float a = 0.f;
#pragma unroll
    for (int d4 = 0; d4 < 64; ++d4) {   // strict sequential-d order (matches exact path)
      float4 qv = *(const float4*)(qr + d4 * 4);
      float4 xv = *(const float4*)(&xrow[d4 * 4]);
      a = fmaf(xv.x, qv.x, a); a = fmaf(xv.y, qv.y, a);
      a = fmaf(xv.z, qv.z, a); a = fmaf(xv.w, qv.w, a);
    }
    sv[tid] = a; si[tid] = tid;
    __syncthreads();
    for (int s = 128; s >= 1; s >>= 1) {
      if (tid < s) {
        float vo = sv[tid + s]; int io = si[tid + s];
        if (vo > sv[tid] || (vo == sv[tid] && io < si[tid])) { sv[tid] = vo; si[tid] = io; }
      }
      __syncthreads();
    }
    int news = si[0];
    if (news != olds && tid == 0) {
      hard[(size_t)tokid * NQQ + olds] = 0.f;
      hard[(size_t)tokid * NQQ + news] = 1.f;
      idxa[tokid] = (unsigned char)news;
    }
    __syncthreads();
  }
}

// reduce v2: compact-then-process. S[b, slot, :] = sum of x rows whose idx==slot.
// block = (b, slot-group of 16); no global atomics; exclusive S region per block.
__global__ __launch_bounds__(512) void reduce_kernel(
    const float* __restrict__ x, const unsigned char* __restrict__ idxa,
    float* __restrict__ S) {
  __shared__ unsigned char  idx_l[NN];        // 8 KB
  __shared__ unsigned short list_l[NN];       // 16 KB (worst-case all tokens one sg)
  __shared__ float accs[2][16][DMODEL];       // 32 KB
  __shared__ unsigned lcnt;
  const int tid = threadIdx.x;
  const int b  = blockIdx.x >> 4;
  const int sg = blockIdx.x & 15;
  const int h  = tid >> 8;                    // half
  const int d  = tid & 255;

  // stage idx bytes (512 x 16B) and keep own 16 bytes in regs
  uint4 myidx = ((const uint4*)(idxa + (size_t)b * NN))[tid];
  ((uint4*)idx_l)[tid] = myidx;
  float* af = &accs[0][0][0];
#pragma unroll
  for (int i = 0; i < 16; ++i) af[i * 512 + tid] = 0.f;
  if (tid == 0) lcnt = 0u;
  __syncthreads();

  // ---- phase 1: parallel compaction of matching token ids ----
  {
    unsigned base = (unsigned)tid * 16u;
    unsigned words[4] = {myidx.x, myidx.y, myidx.z, myidx.w};
#pragma unroll
    for (int wi = 0; wi < 4; ++wi)
#pragma unroll
      for (int j = 0; j < 4; ++j) {
        int s = (words[wi] >> (8 * j)) & 255;
        if ((s >> 4) == sg) {
          unsigned pos = atomicAdd(&lcnt, 1u);
          list_l[pos] = (unsigned short)(base + wi * 4 + j);
        }
      }
  }
  __syncthreads();

  // ---- phase 2: process compacted list, 4-wide load pipeline ----
  const int cnt_ = (int)lcnt;
  const float* xb = x + (size_t)b * NN * DMODEL + d;
  float* myacc = &accs[h][0][0] + d;
  int start = (h * cnt_) >> 1;
  int end   = ((h + 1) * cnt_) >> 1;
  int i = start;
  for (; i + 4 <= end; i += 4) {
    int na = list_l[i], nb = list_l[i + 1], nc = list_l[i + 2], nd = list_l[i + 3];
    float va = xb[(size_t)na * DMODEL];
    float vb = xb[(size_t)nb * DMODEL];
    float vc = xb[(size_t)nc * DMODEL];
    float vd = xb[(size_t)nd * DMODEL];
    myacc[(idx_l[na] & 15) * DMODEL] += va;
    myacc[(idx_l[nb] & 15) * DMODEL] += vb;
    myacc[(idx_l[nc] & 15) * DMODEL] += vc;
    myacc[(idx_l[nd] & 15) * DMODEL] += vd;
  }
  for (; i < end; ++i) {
    int n = list_l[i];
    myacc[(idx_l[n] & 15) * DMODEL] += xb[(size_t)n * DMODEL];
  }
  __syncthreads();

  // ---- write S (exclusive region): 16 rows x 256 ----
#pragma unroll
  for (int ii = 0; ii < 8; ++ii) {
    int u = ii * 512 + tid;
    int ss = u >> 8, dd = u & 255;
    S[((size_t)b * NQQ + sg * 16 + ss) * DMODEL + dd] = accs[0][ss][dd] + accs[1][ss][dd];
  }
}

// out[b,s,d] = sum_dm S[b,s,dm] * MT[dm,d]
__global__ __launch_bounds__(256) void out_kernel(
    const float* __restrict__ S, const float* __restrict__ MT,
    float* __restrict__ out) {
  __shared__ float srow[8][DMODEL];
  const int tid = threadIdx.x;
  const int r0 = blockIdx.x * 8;
#pragma unroll
  for (int i = 0; i < 8; ++i) srow[i][tid] = S[(size_t)(r0 + i) * DMODEL + tid];
  __syncthreads();
  float a[8];
#pragma unroll
  for (int i = 0; i < 8; ++i) a[i] = 0.f;
  for (int dm = 0; dm < DMODEL; ++dm) {
    float m = MT[(size_t)dm * DMODEL + tid];
#pragma unroll
    for (int i = 0; i < 8; ++i) a[i] = fmaf(srow[i][dm], m, a[i]);
  }
#pragma unroll
  for (int i = 0; i < 8; ++i) out[(size_t)(r0 + i) * DMODEL + tid] = a[i];
}

extern "C" void kernel_launch(void* const* d_in, const int* in_sizes, int n_in,
                              void* d_out, int out_size, void* d_ws, size_t ws_size,
                              hipStream_t stream) {
  const float* x   = (const float*)d_in[0];
  const float* q   = (const float*)d_in[1];
  const float* wks = (const float*)d_in[2];
  const float* wvs = (const float*)d_in[3];
  const float* wfc = (const float*)d_in[4];

  float* out  = (float*)d_out;                       // (16,256,256)
  float* hard = out + (size_t)BB * NQQ * DMODEL;     // (16,8192,256)

  float* qk = (float*)d_ws;                          // 65536 f
  float* MT = qk + 65536;                            // 65536 f
  float* S  = MT + 65536;                            // 1048576 f (4 MB)
  unsigned* cnt  = (unsigned*)(S + 1048576);         // 64 u32 (pad)
  unsigned* list = cnt + 64;                         // CAP u32
  unsigned short* qhf = (unsigned short*)(list + CAP);   // 65536 bf16
  unsigned short* qlf = qhf + 65536;                     // 65536 bf16
  unsigned char*  idxa = (unsigned char*)(qlf + 65536);  // 131072 bytes

  hipMemsetAsync(cnt, 0, 256, stream);
  prep_kernel<<<2 * NQQ, 256, 0, stream>>>(q, wks, wvs, wfc, qk, MT, qhf, qlf);
  score_kernel<<<dim3(NN / TOK, BB), 256, 0, stream>>>(x, qhf, qlf, hard, idxa, cnt, list);
  recheck_kernel<<<2048, 256, 0, stream>>>(x, qk, cnt, list, hard, idxa);
  reduce_kernel<<<BB * 16, 512, 0, stream>>>(x, idxa, S);
  out_kernel<<<(BB * NQQ) / 8, 256, 0, stream>>>(S, MT, out);
}

// Round 11
// 178.429 us; speedup vs baseline: 3.1398x; 1.0411x over previous
//
#include <hip/hip_runtime.h>

#define BB 16
#define NN 8192
#define DMODEL 256
#define DKK 64
#define DVV 64
#define NQQ 256
#define TOK 32
#define MARGIN 0.02f
#define CAP 32768

typedef __attribute__((ext_vector_type(8))) short bf16x8;
typedef __attribute__((ext_vector_type(4))) float f32x4;

// RNE split of f32 into bf16 hi + bf16 lo (x ~= hi + lo, |err| ~ 2^-17 |x|)
__device__ __forceinline__ void split_bf16(float v, unsigned short& h, unsigned short& lo) {
  unsigned u = __float_as_uint(v);
  unsigned hr = (u + 0x7FFFu + ((u >> 16) & 1u)) & 0xFFFF0000u;
  h = (unsigned short)(hr >> 16);
  float r = v - __uint_as_float(hr);
  unsigned ul = __float_as_uint(r);
  lo = (unsigned short)((ul + 0x7FFFu + ((ul >> 16) & 1u)) >> 16);
}

// prep: qk = q @ w_ks (f32, for recheck), split-fragments qhf/qlf, MT = (w_fc @ w_vs)^T
__global__ __launch_bounds__(256) void prep_kernel(
    const float* __restrict__ q, const float* __restrict__ w_ks,
    const float* __restrict__ w_vs, const float* __restrict__ w_fc,
    float* __restrict__ qk, float* __restrict__ MT,
    unsigned short* __restrict__ qhf, unsigned short* __restrict__ qlf) {
  __shared__ float sbuf[DKK];
  const int tid = threadIdx.x;
  const int blk = blockIdx.x;
  if (blk < NQQ) {
    const int s = blk;
    if (tid < DKK) sbuf[tid] = q[s * DKK + tid];
    __syncthreads();
    float acc = 0.f;
#pragma unroll
    for (int k = 0; k < DKK; ++k) acc = fmaf(sbuf[k], w_ks[k * DMODEL + tid], acc);
    qk[s * DMODEL + tid] = acc;
    // B fragment layout: elem idx = ((kstep*16 + stile)*64 + (kg*16 + s15))*8 + jj
    int d = tid;
    int kstep = d >> 5, kg = (d >> 3) & 3, jj = d & 7;
    int stile = s >> 4, s15 = s & 15;
    int e = (((kstep * 16 + stile) * 64) + (kg * 16 + s15)) * 8 + jj;
    unsigned short hb, lb;
    split_bf16(acc, hb, lb);
    qhf[e] = hb; qlf[e] = lb;
  } else {
    const int dm = blk - NQQ;
    if (tid < DVV) sbuf[tid] = w_vs[tid * DMODEL + dm];
    __syncthreads();
    float acc = 0.f;
#pragma unroll
    for (int v = 0; v < DVV; ++v) acc = fmaf(w_fc[tid * DVV + v], sbuf[v], acc);
    MT[dm * DMODEL + tid] = acc;
  }
}

// one k-step: prefetch B for k+1, FENCE (no sinking), then 24 MFMAs for k
#define KSTEP(kk, Bhc, Blc, Bhn, Bln, PRE)                                              \
  {                                                                                     \
    if (PRE) {                                                                          \
      _Pragma("unroll")                                                                 \
      for (int j = 0; j < 4; ++j) {                                                     \
        Bhn[j] = bh[(((kk) + 1) * 16 + w * 4 + j) * 64 + l];                            \
        Bln[j] = bl[(((kk) + 1) * 16 + w * 4 + j) * 64 + l];                            \
      }                                                                                 \
      __builtin_amdgcn_sched_barrier(0);  /* pin: loads issue before k's MFMAs */       \
    }                                                                                   \
    _Pragma("unroll")                                                                   \
    for (int i = 0; i < 2; ++i) {                                                       \
      bf16x8 Ah = *(const bf16x8*)(&xs_h[(((kk) * 2 + i) * 64 + l) * 8]);               \
      bf16x8 Al = *(const bf16x8*)(&xs_l[(((kk) * 2 + i) * 64 + l) * 8]);               \
      _Pragma("unroll")                                                                 \
      for (int j = 0; j < 4; ++j) {                                                     \
        acc[i][j] = __builtin_amdgcn_mfma_f32_16x16x32_bf16(Ah, Bhc[j], acc[i][j], 0, 0, 0); \
        acc[i][j] = __builtin_amdgcn_mfma_f32_16x16x32_bf16(Ah, Blc[j], acc[i][j], 0, 0, 0); \
        acc[i][j] = __builtin_amdgcn_mfma_f32_16x16x32_bf16(Al, Bhc[j], acc[i][j], 0, 0, 0); \
      }                                                                                 \
    }                                                                                   \
  }

// main: split-bf16 MFMA scores (B reg-double-buffered, sched-fenced), top-2 argmax
// + margin list, nontemporal one-hot write, idx write.
__global__ __launch_bounds__(256, 4) void score_kernel(
    const float* __restrict__ x, const unsigned short* __restrict__ qhf,
    const unsigned short* __restrict__ qlf,
    float* __restrict__ hard, unsigned char* __restrict__ idxa,
    unsigned* __restrict__ cnt, unsigned* __restrict__ list) {
  __shared__ unsigned short xs_h[8192];   // [kstep(8)][tile(2)][lane(64)][8] bf16, 16 KB
  __shared__ unsigned short xs_l[8192];   // 16 KB
  __shared__ float rm1[4][TOK];
  __shared__ float rm2[4][TOK];
  __shared__ int   ri1[4][TOK];
  __shared__ int   idx_s[TOK];

  const int tid = threadIdx.x;
  const int w = tid >> 6;       // wave 0..3 -> slot range w*64..w*64+63
  const int l = tid & 63;       // lane
  const int b = blockIdx.y;
  const int n0 = blockIdx.x * TOK;
  const float* xbase = x + ((size_t)b * NN + n0) * DMODEL;
  const float4* xb4 = (const float4*)xbase;

  // ---- stage x tile (32 tok x 256 d) as bf16 hi/lo fragments ----
  {
    const int tok = w * 8 + (l >> 3);          // 32 tokens
    const int r   = l & 7;
    const int kg  = r >> 1;                    // (c4>>1)&3
    const int j0  = (r & 1) * 4;
    const int i   = tok >> 4;
    const int t15 = tok & 15;
#pragma unroll
    for (int it = 0; it < 8; ++it) {
      int c4 = it * 8 + r;                     // kstep = it
      float4 v = xb4[tok * 64 + c4];
      int e = (((it * 2 + i) * 64) + (kg * 16 + t15)) * 8 + j0;
      ushort4 hh, ll;
      split_bf16(v.x, hh.x, ll.x);
      split_bf16(v.y, hh.y, ll.y);
      split_bf16(v.z, hh.z, ll.z);
      split_bf16(v.w, hh.w, ll.w);
      *(ushort4*)(&xs_h[e]) = hh;
      *(ushort4*)(&xs_l[e]) = ll;
    }
  }

  // ---- preload B fragments for k=0 (overlaps with staging latency) ----
  const bf16x8* bh = (const bf16x8*)qhf;
  const bf16x8* bl = (const bf16x8*)qlf;
  bf16x8 BhA[4], BlA[4], BhB[4], BlB[4];
#pragma unroll
  for (int j = 0; j < 4; ++j) {
    BhA[j] = bh[(w * 4 + j) * 64 + l];
    BlA[j] = bl[(w * 4 + j) * 64 + l];
  }
  __syncthreads();

  // ---- MFMA: 32 tok x 64 slots per wave; B reg ping-pong hides L2/L3 latency ----
  f32x4 acc[2][4];
#pragma unroll
  for (int i = 0; i < 2; ++i)
#pragma unroll
    for (int j = 0; j < 4; ++j) acc[i][j] = (f32x4){0.f, 0.f, 0.f, 0.f};

  KSTEP(0, BhA, BlA, BhB, BlB, true)
  KSTEP(1, BhB, BlB, BhA, BlA, true)
  KSTEP(2, BhA, BlA, BhB, BlB, true)
  KSTEP(3, BhB, BlB, BhA, BlA, true)
  KSTEP(4, BhA, BlA, BhB, BlB, true)
  KSTEP(5, BhB, BlB, BhA, BlA, true)
  KSTEP(6, BhA, BlA, BhB, BlB, true)
  KSTEP(7, BhB, BlB, BhA, BlA, false)

  // ---- per-token top-2 over this wave's 64 slots ----
  // C/D layout: col(slot) = l&15, row(token) = (l>>4)*4 + reg
  const int s15 = l & 15, g4 = l >> 4;
#pragma unroll
  for (int i = 0; i < 2; ++i) {
#pragma unroll
    for (int rr = 0; rr < 4; ++rr) {
      float m1 = acc[i][0][rr];
      int   i1 = w * 64 + s15;
      float m2 = -1e30f;
#pragma unroll
      for (int j = 1; j < 4; ++j) {
        float v = acc[i][j][rr];
        int   s = w * 64 + j * 16 + s15;
        if (v > m1) { m2 = m1; m1 = v; i1 = s; }
        else if (v > m2) m2 = v;
      }
#pragma unroll
      for (int off = 1; off < 16; off <<= 1) {
        float om1 = __shfl_xor(m1, off, 64);
        int   oi1 = __shfl_xor(i1, off, 64);
        float om2 = __shfl_xor(m2, off, 64);
        if (om1 > m1 || (om1 == m1 && oi1 < i1)) { m2 = fmaxf(m1, om2); m1 = om1; i1 = oi1; }
        else { m2 = fmaxf(m2, om1); }
      }
      if (s15 == 0) {
        int t = i * 16 + g4 * 4 + rr;
        rm1[w][t] = m1; rm2[w][t] = m2; ri1[w][t] = i1;
      }
    }
  }
  __syncthreads();

  // ---- cross-wave merge (ascending slot ranges -> first-index tie-break) ----
  if (tid < TOK) {
    float m1 = rm1[0][tid]; int i1 = ri1[0][tid]; float m2 = rm2[0][tid];
#pragma unroll
    for (int ww = 1; ww < 4; ++ww) {
      float om1 = rm1[ww][tid]; int oi1 = ri1[ww][tid]; float om2 = rm2[ww][tid];
      if (om1 > m1) { m2 = fmaxf(m1, om2); m1 = om1; i1 = oi1; }
      else { m2 = fmaxf(m2, om1); }
    }
    idx_s[tid] = i1;
    idxa[(size_t)b * NN + n0 + tid] = (unsigned char)i1;
    if (m1 - m2 <= MARGIN) {   // ambiguous under split-bf16 error -> f32 recheck
      unsigned pos = atomicAdd(cnt, 1u);
      if (pos < CAP) list[pos] = (((unsigned)(b * NN + n0 + tid)) << 8) | (unsigned)i1;
    }
  }
  __syncthreads();

  // ---- one-hot write: nontemporal (don't evict B fragments from L2) ----
  f32x4* hbase = (f32x4*)(hard + ((size_t)b * NN + n0) * NQQ);
#pragma unroll
  for (int it = 0; it < 8; ++it) {
    int u = it * 256 + tid;
    int tk = u >> 6;
    int s0 = (u & 63) * 4;
    int tgt = idx_s[tk];
    f32x4 h;
    h[0] = (s0 + 0 == tgt) ? 1.f : 0.f;
    h[1] = (s0 + 1 == tgt) ? 1.f : 0.f;
    h[2] = (s0 + 2 == tgt) ? 1.f : 0.f;
    h[3] = (s0 + 3 == tgt) ? 1.f : 0.f;
    __builtin_nontemporal_store(h, &hbase[u]);
  }
}

// recheck: exact-f32 scores for ambiguous tokens; patch one-hot + idx byte on flip
__global__ __launch_bounds__(256) void recheck_kernel(
    const float* __restrict__ x, const float* __restrict__ qk,
    const unsigned* __restrict__ cnt, const unsigned* __restrict__ list,
    float* __restrict__ hard, unsigned char* __restrict__ idxa) {
  __shared__ float xrow[DMODEL];
  __shared__ float sv[NQQ];
  __shared__ int   si[NQQ];
  const int tid = threadIdx.x;
  unsigned nc = cnt[0];
  int nA = (int)(nc < (unsigned)CAP ? nc : (unsigned)CAP);
  for (int e = blockIdx.x; e < nA; e += gridDim.x) {
    unsigned pk = list[e];
    int tokid = (int)(pk >> 8);
    int olds  = (int)(pk & 255u);
    const float* xr = x + (size_t)tokid * DMODEL;
    xrow[tid] = xr[tid];
    __syncthreads();
    const float* qr = qk + (size_t)tid * DMODEL;
    float a = 0.f;
#pragma unroll
    for (int d4 = 0; d4 < 64; ++d4) {   // strict sequential-d order (matches exact path)
      float4 qv = *(const float4*)(qr + d4 * 4);
      float4 xv = *(const float4*)(&xrow[d4 * 4]);
      a = fmaf(xv.x, qv.x, a); a = fmaf(xv.y, qv.y, a);
      a = fmaf(xv.z, qv.z, a); a = fmaf(xv.w, qv.w, a);
    }
    sv[tid] = a; si[tid] = tid;
    __syncthreads();
    for (int s = 128; s >= 1; s >>= 1) {
      if (tid < s) {
        float vo = sv[tid + s]; int io = si[tid + s];
        if (vo > sv[tid] || (vo == sv[tid] && io < si[tid])) { sv[tid] = vo; si[tid] = io; }
      }
      __syncthreads();
    }
    int news = si[0];
    if (news != olds && tid == 0) {
      hard[(size_t)tokid * NQQ + olds] = 0.f;
      hard[(size_t)tokid * NQQ + news] = 1.f;
      idxa[tokid] = (unsigned char)news;
    }
    __syncthreads();
  }
}

// reduce v2: compact-then-process. S[b, slot, :] = sum of x rows whose idx==slot.
// block = (b, slot-group of 16); no global atomics; exclusive S region per block.
__global__ __launch_bounds__(512) void reduce_kernel(
    const float* __restrict__ x, const unsigned char* __restrict__ idxa,
    float* __restrict__ S) {
  __shared__ unsigned char  idx_l[NN];        // 8 KB
  __shared__ unsigned short list_l[NN];       // 16 KB (worst-case all tokens one sg)
  __shared__ float accs[2][16][DMODEL];       // 32 KB
  __shared__ unsigned lcnt;
  const int tid = threadIdx.x;
  const int b  = blockIdx.x >> 4;
  const int sg = blockIdx.x & 15;
  const int h  = tid >> 8;                    // half
  const int d  = tid & 255;

  // stage idx bytes (512 x 16B) and keep own 16 bytes in regs
  uint4 myidx = ((const uint4*)(idxa + (size_t)b * NN))[tid];
  ((uint4*)idx_l)[tid] = myidx;
  float* af = &accs[0][0][0];
#pragma unroll
  for (int i = 0; i < 16; ++i) af[i * 512 + tid] = 0.f;
  if (tid == 0) lcnt = 0u;
  __syncthreads();

  // ---- phase 1: parallel compaction of matching token ids ----
  {
    unsigned base = (unsigned)tid * 16u;
    unsigned words[4] = {myidx.x, myidx.y, myidx.z, myidx.w};
#pragma unroll
    for (int wi = 0; wi < 4; ++wi)
#pragma unroll
      for (int j = 0; j < 4; ++j) {
        int s = (words[wi] >> (8 * j)) & 255;
        if ((s >> 4) == sg) {
          unsigned pos = atomicAdd(&lcnt, 1u);
          list_l[pos] = (unsigned short)(base + wi * 4 + j);
        }
      }
  }
  __syncthreads();

  // ---- phase 2: process compacted list, 4-wide load pipeline ----
  const int cnt_ = (int)lcnt;
  const float* xb = x + (size_t)b * NN * DMODEL + d;
  float* myacc = &accs[h][0][0] + d;
  int start = (h * cnt_) >> 1;
  int end   = ((h + 1) * cnt_) >> 1;
  int i = start;
  for (; i + 4 <= end; i += 4) {
    int na = list_l[i], nb = list_l[i + 1], nc = list_l[i + 2], nd = list_l[i + 3];
    float va = xb[(size_t)na * DMODEL];
    float vb = xb[(size_t)nb * DMODEL];
    float vc = xb[(size_t)nc * DMODEL];
    float vd = xb[(size_t)nd * DMODEL];
    myacc[(idx_l[na] & 15) * DMODEL] += va;
    myacc[(idx_l[nb] & 15) * DMODEL] += vb;
    myacc[(idx_l[nc] & 15) * DMODEL] += vc;
    myacc[(idx_l[nd] & 15) * DMODEL] += vd;
  }
  for (; i < end; ++i) {
    int n = list_l[i];
    myacc[(idx_l[n] & 15) * DMODEL] += xb[(size_t)n * DMODEL];
  }
  __syncthreads();

  // ---- write S (exclusive region): 16 rows x 256 ----
#pragma unroll
  for (int ii = 0; ii < 8; ++ii) {
    int u = ii * 512 + tid;
    int ss = u >> 8, dd = u & 255;
    S[((size_t)b * NQQ + sg * 16 + ss) * DMODEL + dd] = accs[0][ss][dd] + accs[1][ss][dd];
  }
}

// out[b,s,d] = sum_dm S[b,s,dm] * MT[dm,d]
__global__ __launch_bounds__(256) void out_kernel(
    const float* __restrict__ S, const float* __restrict__ MT,
    float* __restrict__ out) {
  __shared__ float srow[8][DMODEL];
  const int tid = threadIdx.x;
  const int r0 = blockIdx.x * 8;
#pragma unroll
  for (int i = 0; i < 8; ++i) srow[i][tid] = S[(size_t)(r0 + i) * DMODEL + tid];
  __syncthreads();
  float a[8];
#pragma unroll
  for (int i = 0; i < 8; ++i) a[i] = 0.f;
  for (int dm = 0; dm < DMODEL; ++dm) {
    float m = MT[(size_t)dm * DMODEL + tid];
#pragma unroll
    for (int i = 0; i < 8; ++i) a[i] = fmaf(srow[i][dm], m, a[i]);
  }
#pragma unroll
  for (int i = 0; i < 8; ++i) out[(size_t)(r0 + i) * DMODEL + tid] = a[i];
}

extern "C" void kernel_launch(void* const* d_in, const int* in_sizes, int n_in,
                              void* d_out, int out_size, void* d_ws, size_t ws_size,
                              hipStream_t stream) {
  const float* x   = (const float*)d_in[0];
  const float* q   = (const float*)d_in[1];
  const float* wks = (const float*)d_in[2];
  const float* wvs = (const float*)d_in[3];
  const float* wfc = (const float*)d_in[4];

  float* out  = (float*)d_out;                       // (16,256,256)
  float* hard = out + (size_t)BB * NQQ * DMODEL;     // (16,8192,256)

  float* qk = (float*)d_ws;                          // 65536 f
  float* MT = qk + 65536;                            // 65536 f
  float* S  = MT + 65536;                            // 1048576 f (4 MB)
  unsigned* cnt  = (unsigned*)(S + 1048576);         // 64 u32 (pad)
  unsigned* list = cnt + 64;                         // CAP u32
  unsigned short* qhf = (unsigned short*)(list + CAP);   // 65536 bf16
  unsigned short* qlf = qhf + 65536;                     // 65536 bf16
  unsigned char*  idxa = (unsigned char*)(qlf + 65536);  // 131072 bytes

  (void)hipMemsetAsync(cnt, 0, 256, stream);
  prep_kernel<<<2 * NQQ, 256, 0, stream>>>(q, wks, wvs, wfc, qk, MT, qhf, qlf);
  score_kernel<<<dim3(NN / TOK, BB), 256, 0, stream>>>(x, qhf, qlf, hard, idxa, cnt, list);
  recheck_kernel<<<2048, 256, 0, stream>>>(x, qk, cnt, list, hard, idxa);
  reduce_kernel<<<BB * 16, 512, 0, stream>>>(x, idxa, S);
  out_kernel<<<(BB * NQQ) / 8, 256, 0, stream>>>(S, MT, out);
}